// Round 3
// baseline (342.763 us; speedup 1.0000x reference)
//
#include <hip/hip_runtime.h>

// ---------------- problem constants ----------------
constexpr int NB    = 32;
constexpr int HW0   = 320 * 320;
constexpr int HW1   = 160 * 160;
constexpr int N0    = NB * HW0;           // 3,276,800
constexpr int N1    = NB * HW1;           // 819,200
constexpr int HW0_4 = HW0 / 4;            // 25,600
constexpr int HW1_4 = HW1 / 4;            // 6,400
constexpr int BLK   = 256;

// score sub-grid: one float4-pack (4 px) per thread
constexpr int SB0 = N0 / 4 / BLK;         // 3200
constexpr int SB1 = N1 / 4 / BLK;         // 800
constexpr int SBT = SB0 + SB1;            // 4000
// bbox sub-grid: 2 float4 per stream per thread
constexpr int BT0 = N0 / 2;               // threads branch0 (N0 f4s / 2)
constexpr int BT1 = N1 / 2;
constexpr int BB0 = BT0 / BLK;            // 6400
constexpr int BB1 = BT1 / BLK;            // 1600
constexpr int PASS1_GRID = SBT + BB0 + BB1;  // 12000
// refine: 4 packs (16 px) per thread
constexpr int RT0 = N0 / 16;              // 204800 threads
constexpr int RT1 = N1 / 16;              // 51200
constexpr int RB0 = RT0 / BLK;            // 800
constexpr int RB1 = RT1 / BLK;            // 200
constexpr int GRID_R = RB0 + RB1;         // 1000

constexpr unsigned long long MASK40 = (1ull << 40) - 1;
constexpr float CE_SCALE = 65536.0f;
constexpr int REP1 = 16;                  // level-1 hist replicas
constexpr int REP2 = 8;                   // refine hist replicas

// ---------------- workspace layout (bytes) ----------------
constexpr size_t CTRL_OFF  = 0;                                   // BranchCtrl[2] = 256
constexpr size_t H1C_OFF   = 256;                                 // u32 [2][16][1024]
constexpr size_t H1E_OFF   = H1C_OFF + 2 * REP1 * 1024 * 4;       // u64 [2][16][1024]
constexpr size_t H23C_OFF  = H1E_OFF + 2 * REP1 * 1024 * 8;       // u32 [2][8][3072]
constexpr size_t H23E_OFF  = H23C_OFF + 2 * REP2 * 3072 * 4;      // u64 [2][8][3072]
constexpr size_t ZERO_END  = H23E_OFF + 2 * REP2 * 3072 * 8;      // 983,296
constexpr int    ZERO_WORDS = (int)(ZERO_END / 4);
constexpr size_t PN_OFF    = ZERO_END;                            // u32[4000] pos|neg<<16
constexpr size_t CE0_OFF   = PN_OFF + 4000 * 4;                   // f64[4000]
constexpr size_t D2MS_OFF  = CE0_OFF + 4000 * 8;                  // double2[8000]
constexpr size_t PB_OFF    = ((D2MS_OFF + 8000 * 16 + 255) / 256) * 256;  // u32[N0+N1]
constexpr size_t CES_OFF   = PB_OFF + (size_t)(N0 + N1) * 4;      // f32[N0+N1]
constexpr size_t WS_NEED   = CES_OFF + (size_t)(N0 + N1) * 4;     // ~33.9 MB

struct BranchCtrl {
    unsigned pos_num, neg_num, sel1, sel2;
    unsigned target, cnt_below, done, pad1;
    unsigned long long ce_below_fx;
    double ce0, d2, ms;
    double loss_score, loss_bbox;
    double pad2[6];   // -> 128 B
};

__device__ inline BranchCtrl* ctrl_of(void* ws, int br) { return (BranchCtrl*)((char*)ws + CTRL_OFF) + br; }
__device__ inline unsigned*  h1c(void* ws)  { return (unsigned*)((char*)ws + H1C_OFF); }
__device__ inline unsigned long long* h1e(void* ws) { return (unsigned long long*)((char*)ws + H1E_OFF); }
__device__ inline unsigned*  h23c(void* ws) { return (unsigned*)((char*)ws + H23C_OFF); }
__device__ inline unsigned long long* h23e(void* ws) { return (unsigned long long*)((char*)ws + H23E_OFF); }
__device__ inline unsigned*  pn_part(void* ws)  { return (unsigned*)((char*)ws + PN_OFF); }
__device__ inline double*    ce0_part(void* ws) { return (double*)((char*)ws + CE0_OFF); }
__device__ inline double2*   d2ms_part(void* ws){ return (double2*)((char*)ws + D2MS_OFF); }
__device__ inline unsigned*  pb_of(void* ws, int br) { return (unsigned*)((char*)ws + PB_OFF) + (br ? (size_t)N0 : 0); }
__device__ inline float*     ce_of(void* ws, int br) { return (float*)((char*)ws + CES_OFF) + (br ? (size_t)N0 : 0); }

// ---------------- device helpers ----------------
__device__ __forceinline__ void softmax2(float a, float c, float& p0, float& p1) {
    float m  = fmaxf(a, c);
    float e0 = __expf(a - m);
    float e1 = __expf(c - m);
    float inv = 1.0f / (e0 + e1);
    p0 = e0 * inv;
    p1 = e1 * inv;
}

template <typename T>
__device__ __forceinline__ T block_reduce(T v, T* scr) {
#pragma unroll
    for (int o = 32; o > 0; o >>= 1) v += __shfl_down(v, o, 64);
    const int lane = threadIdx.x & 63;
    const int w    = threadIdx.x >> 6;
    __syncthreads();
    if (lane == 0) scr[w] = v;
    __syncthreads();
    return scr[0] + scr[1] + scr[2] + scr[3];
}

// ---------------- kernels ----------------
__global__ __launch_bounds__(256) void zero_ws_k(unsigned* p, int n) {
    int i = blockIdx.x * BLK + threadIdx.x;
    if (i < n) p[i] = 0;
}

// ---- pass1: score blocks [0,SBT) + bbox blocks [SBT, PASS1_GRID) ----
template <int BR, bool STORED>
__device__ void score_body(const float4* __restrict__ score, const float4* __restrict__ glabel,
                           void* ws, int blk, int sb_global,
                           unsigned long long* hAB, double* dscr, unsigned* uscr)
{
    constexpr int HW4 = BR ? HW1_4 : HW0_4;
    const int idx = blk * BLK + (int)threadIdx.x;
    const int b = idx / HW4;
    const int r = idx - b * HW4;

    const float4 s0 = score[(b * 2 + 0) * HW4 + r];
    const float4 s1 = score[(b * 2 + 1) * HW4 + r];
    const float4 g0 = glabel[(b * 6 + 0) * HW4 + r];
    const float4 g1 = glabel[(b * 6 + 1) * HW4 + r];

    unsigned pncnt = 0;           // pos | neg<<16
    float ce0f = 0.0f;
    uint4 pk; float4 cef;
    unsigned* pkp = &pk.x; float* cep = &cef.x;
    unsigned bins[4]; unsigned long long vals[4];
#pragma unroll
    for (int j = 0; j < 4; j++) {
        float p0, p1;
        softmax2((&s0.x)[j], (&s1.x)[j], p0, p1);
        float l0 = (&g0.x)[j], l1 = (&g1.x)[j];
        bool pos = l0 > 0.5f;
        bool neg = l1 > 0.5f;
        pncnt += (pos ? 1u : 0u) + (neg ? 0x10000u : 0u);
        ce0f += pos ? (-l0 * __logf(p0)) : 0.0f;
        float cv = -l1 * __logf(p1);
        unsigned pb = __float_as_uint(p1);
        pkp[j] = pb | (neg ? 0x80000000u : 0u);
        cep[j] = cv;
        bins[j] = (neg ? 0u : 512u) + (pb >> 21);
        vals[j] = (1ull << 40) | (unsigned long long)__float2uint_rn(cv * CE_SCALE);
    }
    if (STORED) {
        ((uint4*)pb_of(ws, BR))[idx] = pk;
        ((float4*)ce_of(ws, BR))[idx] = cef;
    }
    // dedup within the 4
#pragma unroll
    for (int j = 0; j < 4; j++) {
        if (bins[j] != 0xFFFFFFFFu) {
            unsigned long long v = vals[j];
#pragma unroll
            for (int k = j + 1; k < 4; k++)
                if (bins[k] == bins[j]) { v += vals[k]; bins[k] = 0xFFFFFFFFu; }
            atomicAdd(&hAB[bins[j]], v);
        }
    }
    __syncthreads();
    // flush LDS hist to replicated global hist
    const int rep = sb_global & (REP1 - 1);
    unsigned* gc = h1c(ws) + ((size_t)BR * REP1 + rep) * 1024;
    unsigned long long* ge = h1e(ws) + ((size_t)BR * REP1 + rep) * 1024;
    for (int i = threadIdx.x; i < 1024; i += BLK) {
        unsigned long long v = hAB[i];
        if (v) {
            atomicAdd(&gc[i], (unsigned)(v >> 40));
            atomicAdd(&ge[i], v & MASK40);
        }
    }
    unsigned PN = block_reduce(pncnt, uscr);
    double CE0 = block_reduce((double)ce0f, dscr);
    if (threadIdx.x == 0) {
        pn_part(ws)[sb_global] = PN;
        ce0_part(ws)[sb_global] = CE0;
    }
}

template <int BR>
__device__ void bbox_body(const float4* __restrict__ bbox, const float4* __restrict__ gmask,
                          const float4* __restrict__ glabel, void* ws, int blk, int bb_global,
                          double* dscr)
{
    constexpr int HW4 = BR ? HW1_4 : HW0_4;
    constexpr int T   = BR ? BT1 : BT0;     // threads in this sub-grid
    const int t = blk * BLK + (int)threadIdx.x;

    const int i0 = t;
    const int i1 = t + T;
    const int b0 = i0 / (4 * HW4);
    const int b1 = i1 / (4 * HW4);
    const float4 bbA = bbox[i0];
    const float4 bbB = bbox[i1];
    const float4 gmA = gmask[i0 + (2 * b0 + 2) * HW4];
    const float4 gmB = gmask[i1 + (2 * b1 + 2) * HW4];
    const float4 glA = glabel[i0 + (2 * b0 + 2) * HW4];
    const float4 glB = glabel[i1 + (2 * b1 + 2) * HW4];

    float d2f = 0.0f, msf = 0.0f;
#pragma unroll
    for (int j = 0; j < 4; j++) {
        float m0 = (&gmA.x)[j];
        float dA = ((&bbA.x)[j] - (&glA.x)[j]) * m0;
        d2f += dA * dA; msf += m0;
        float m1 = (&gmB.x)[j];
        float dB = ((&bbB.x)[j] - (&glB.x)[j]) * m1;
        d2f += dB * dB; msf += m1;
    }
    double D2 = block_reduce((double)d2f, dscr);
    double MS = block_reduce((double)msf, dscr);
    if (threadIdx.x == 0) d2ms_part(ws)[bb_global] = make_double2(D2, MS);
}

template <bool STORED>
__global__ __launch_bounds__(256) void pass1(
    const float4* __restrict__ sc0, const float4* __restrict__ bb0,
    const float4* __restrict__ mk0, const float4* __restrict__ lb0,
    const float4* __restrict__ sc1, const float4* __restrict__ bb1,
    const float4* __restrict__ mk1, const float4* __restrict__ lb1,
    void* ws)
{
    __shared__ unsigned long long hAB[1024];
    __shared__ double dscr[4];
    __shared__ unsigned uscr[4];
    const int bid = blockIdx.x;
    if (bid < SBT) {
        for (int i = threadIdx.x; i < 1024; i += BLK) hAB[i] = 0;
        __syncthreads();
        if (bid < SB0) score_body<0, STORED>(sc0, lb0, ws, bid, bid, hAB, dscr, uscr);
        else           score_body<1, STORED>(sc1, lb1, ws, bid - SB0, bid, hAB, dscr, uscr);
    } else if (bid < SBT + BB0) {
        bbox_body<0>(bb0, mk0, lb0, ws, bid - SBT, bid - SBT, dscr);
    } else {
        bbox_body<1>(bb1, mk1, lb1, ws, bid - SBT - BB0, bid - SBT, dscr);
    }
}

// ---- refine: histogram (count+ce) of elements inside the selected prefix bin ----
template <int BR, bool STORED>
__device__ void refine_body(const float4* __restrict__ score, const float4* __restrict__ glabel,
                            void* ws, int blk, int level, unsigned long long* h)
{
    BranchCtrl* c = ctrl_of(ws, BR);
    const unsigned haspos = (c->pos_num > 0) ? 1u : 0u;
    unsigned selmatch, scmp, sbin, bmsk;
    if (level == 2) { selmatch = c->sel1;                   scmp = 21; sbin = 10; bmsk = 0x7FFu; }
    else            { selmatch = (c->sel1 << 11) | c->sel2; scmp = 10; sbin = 0;  bmsk = 0x3FFu; }

    constexpr int T = BR ? RT1 : RT0;
    const int base = blk * BLK + (int)threadIdx.x;

    unsigned pkv[16]; float cev[16];
    if (STORED) {
        const uint4* pb4 = (const uint4*)pb_of(ws, BR);
        uint4 q[4];
#pragma unroll
        for (int i = 0; i < 4; i++) q[i] = pb4[base + i * T];
#pragma unroll
        for (int i = 0; i < 4; i++) {
            pkv[i*4+0]=q[i].x; pkv[i*4+1]=q[i].y; pkv[i*4+2]=q[i].z; pkv[i*4+3]=q[i].w;
        }
        // decide which ce packs we need, then issue all needed loads
        bool need[4];
#pragma unroll
        for (int i = 0; i < 4; i++) {
            bool any = false;
#pragma unroll
            for (int j = 0; j < 4; j++) {
                unsigned raw = pkv[i*4+j];
                unsigned pb  = raw & 0x7FFFFFFFu;
                unsigned npb = haspos ? ((raw >> 31) ? pb : 0u) : pb;
                any |= ((npb >> scmp) == selmatch);
            }
            need[i] = any;
        }
        const float4* ce4 = (const float4*)ce_of(ws, BR);
        float4 e[4];
#pragma unroll
        for (int i = 0; i < 4; i++)
            if (need[i]) e[i] = ce4[base + i * T];
#pragma unroll
        for (int i = 0; i < 4; i++) {
            cev[i*4+0] = e[i].x; cev[i*4+1] = e[i].y; cev[i*4+2] = e[i].z; cev[i*4+3] = e[i].w;
        }
    } else {
        constexpr int HW4 = BR ? HW1_4 : HW0_4;
#pragma unroll
        for (int i = 0; i < 4; i++) {
            int id = base + i * T;
            int b = id / HW4;
            int r = id - b * HW4;
            float4 s0 = score[(b * 2 + 0) * HW4 + r];
            float4 s1 = score[(b * 2 + 1) * HW4 + r];
            float4 g1 = glabel[(b * 6 + 1) * HW4 + r];
#pragma unroll
            for (int j = 0; j < 4; j++) {
                float p0, p1;
                softmax2((&s0.x)[j], (&s1.x)[j], p0, p1);
                pkv[i*4+j] = __float_as_uint(p1) | (((&g1.x)[j] > 0.5f) ? 0x80000000u : 0u);
                cev[i*4+j] = -(&g1.x)[j] * __logf(p1);
            }
        }
    }

    unsigned zc = 0;                    // bin-0 (npb==0) storm accumulator
    unsigned long long zce = 0;
#pragma unroll
    for (int i = 0; i < 4; i++) {
        unsigned bins[4]; unsigned long long vals[4];
#pragma unroll
        for (int j = 0; j < 4; j++) {
            unsigned raw = pkv[i*4+j];
            unsigned pb  = raw & 0x7FFFFFFFu;
            unsigned npb = haspos ? ((raw >> 31) ? pb : 0u) : pb;
            bool m = ((npb >> scmp) == selmatch);
            unsigned long long cefx = (unsigned long long)__float2uint_rn(cev[i*4+j] * CE_SCALE);
            if (m && npb == 0) { zc++; zce += cefx; bins[j] = 0xFFFFFFFFu; vals[j] = 0; }
            else { bins[j] = m ? ((npb >> sbin) & bmsk) : 0xFFFFFFFFu; vals[j] = (1ull << 40) | cefx; }
        }
#pragma unroll
        for (int j = 0; j < 4; j++) {
            if (bins[j] != 0xFFFFFFFFu) {
                unsigned long long v = vals[j];
#pragma unroll
                for (int k = j + 1; k < 4; k++)
                    if (bins[k] == bins[j]) { v += vals[k]; bins[k] = 0xFFFFFFFFu; }
                atomicAdd(&h[bins[j]], v);
            }
        }
    }
    if (zc) atomicAdd(&h[0], ((unsigned long long)zc << 40) | zce);
}

template <bool STORED>
__global__ __launch_bounds__(256) void refine_pass(
    const float4* __restrict__ sc0, const float4* __restrict__ lb0,
    const float4* __restrict__ sc1, const float4* __restrict__ lb1,
    void* ws, int level)
{
    int br, blk;
    if (blockIdx.x < RB0) { br = 0; blk = blockIdx.x; }
    else                  { br = 1; blk = blockIdx.x - RB0; }
    if (ctrl_of(ws, br)->done) return;

    __shared__ unsigned long long h[2048];
    const int nb = (level == 2) ? 2048 : 1024;
    for (int i = threadIdx.x; i < nb; i += BLK) h[i] = 0;
    __syncthreads();

    if (br == 0) refine_body<0, STORED>(sc0, lb0, ws, blk, level, h);
    else         refine_body<1, STORED>(sc1, lb1, ws, blk, level, h);

    __syncthreads();
    const int rep = blockIdx.x & (REP2 - 1);
    const int off = (level == 2) ? 0 : 2048;
    unsigned* gc = h23c(ws) + ((size_t)br * REP2 + rep) * 3072 + off;
    unsigned long long* ge = h23e(ws) + ((size_t)br * REP2 + rep) * 3072 + off;
    for (int i = threadIdx.x; i < nb; i += BLK) {
        unsigned long long v = h[i];
        if (v) {
            atomicAdd(&gc[i], (unsigned)(v >> 40));
            atomicAdd(&ge[i], v & MASK40);
        }
    }
}

// ---- scan/select (single block) ----
__global__ __launch_bounds__(256) void scan_pass(void* ws, int level, float* out) {
    const int t = threadIdx.x;
    __shared__ unsigned pref[256];
    __shared__ double dscr[4];
    __shared__ unsigned uscr[4];
    __shared__ unsigned long long qscr[4];
    __shared__ unsigned sh_sel, sh_tnext, sh_cb, sh_ci, sh_hA0;
    __shared__ unsigned shP[2], shN[2];
    __shared__ double shCE0[2];

    if (level == 1) {
        // phase A: reduce per-block partials for both branches
        unsigned long long pk0 = 0, pk1 = 0;
        double ce00 = 0, ce01 = 0, d20 = 0, ms0 = 0, d21 = 0, ms1 = 0;
        const unsigned* pn = pn_part(ws);
        const double* cp = ce0_part(ws);
        for (int i = t; i < SBT; i += BLK) {
            unsigned v = pn[i];
            unsigned long long pv = (unsigned long long)(v & 0xFFFFu) | ((unsigned long long)(v >> 16) << 32);
            if (i < SB0) { pk0 += pv; ce00 += cp[i]; }
            else         { pk1 += pv; ce01 += cp[i]; }
        }
        const double2* dm = d2ms_part(ws);
        for (int i = t; i < BB0 + BB1; i += BLK) {
            double2 d = dm[i];
            if (i < BB0) { d20 += d.x; ms0 += d.y; }
            else         { d21 += d.x; ms1 += d.y; }
        }
        pk0 = block_reduce(pk0, qscr);
        pk1 = block_reduce(pk1, qscr);
        ce00 = block_reduce(ce00, dscr);
        ce01 = block_reduce(ce01, dscr);
        d20 = block_reduce(d20, dscr);
        ms0 = block_reduce(ms0, dscr);
        d21 = block_reduce(d21, dscr);
        ms1 = block_reduce(ms1, dscr);
        if (t == 0) {
            BranchCtrl* c0 = ctrl_of(ws, 0);
            BranchCtrl* c1 = ctrl_of(ws, 1);
            shP[0] = (unsigned)(pk0 & 0xFFFFFFFFu); shN[0] = (unsigned)(pk0 >> 32);
            shP[1] = (unsigned)(pk1 & 0xFFFFFFFFu); shN[1] = (unsigned)(pk1 >> 32);
            shCE0[0] = ce00; shCE0[1] = ce01;
            c0->pos_num = shP[0]; c0->neg_num = shN[0]; c0->ce0 = ce00; c0->d2 = d20; c0->ms = ms0;
            c1->pos_num = shP[1]; c1->neg_num = shN[1]; c1->ce0 = ce01; c1->d2 = d21; c1->ms = ms1;
            c0->loss_bbox = (ms0 > 0.0) ? (d20 / fmax(ms0, 1e-8)) : 0.0;
            c1->loss_bbox = (ms1 > 0.0) ? (d21 / fmax(ms1, 1e-8)) : 0.0;
        }
        __syncthreads();
    }

    for (int br = 0; br < 2; br++) {
        BranchCtrl* c = ctrl_of(ws, br);
        const int N = br ? N1 : N0;
        unsigned target, haspos, negn, P;
        double CE0 = 0.0;

        if (level == 1) {
            P = shP[br]; negn = shN[br]; CE0 = shCE0[br];
            haspos = (P > 0) ? 1u : 0u;
            unsigned k = haspos ? ((5u * P < negn) ? 5u * P : negn) : (unsigned)(N / 10);
            target = (k < 1u) ? 1u : k;
            if (target > (unsigned)N) target = (unsigned)N;
        } else {
            if (c->done) continue;
            target = c->target;
            P = c->pos_num;
            haspos = (P > 0) ? 1u : 0u;
            negn = c->neg_num;
        }

        const int nbins = (level == 1) ? 512 : (level == 2) ? 2048 : 1024;
        const int per = nbins / BLK;   // 2 / 8 / 4

        unsigned long long sumB = 0;
        if (level == 1 && haspos) {
            const unsigned long long* eb = h1e(ws) + (size_t)br * REP1 * 1024;
            unsigned long long s = 0;
            for (int i = 512 + t; i < 1024; i += BLK)
                for (int r = 0; r < REP1; r++) s += eb[r * 1024 + i];
            sumB = block_reduce(s, qscr);
        }

        unsigned cnt[8]; unsigned long long cev[8];
        unsigned s = 0;
        for (int j = 0; j < per; j++) {
            int i = t * per + j;
            unsigned cv; unsigned long long ev;
            if (level == 1) {
                const unsigned* hc = h1c(ws) + (size_t)br * REP1 * 1024;
                const unsigned long long* he = h1e(ws) + (size_t)br * REP1 * 1024;
                unsigned cA = 0; unsigned long long eA = 0;
                for (int r = 0; r < REP1; r++) { cA += hc[r * 1024 + i]; eA += he[r * 1024 + i]; }
                if (haspos) {
                    cv = cA + ((i == 0) ? ((unsigned)N - negn) : 0u);
                    ev = eA + ((i == 0) ? sumB : 0ull);
                    if (i == 0) sh_hA0 = cA;
                } else {
                    unsigned cB = 0; unsigned long long eB = 0;
                    for (int r = 0; r < REP1; r++) { cB += hc[r * 1024 + 512 + i]; eB += he[r * 1024 + 512 + i]; }
                    cv = cA + cB; ev = eA + eB;
                }
            } else {
                const int off = (level == 2) ? 0 : 2048;
                const unsigned* hc = h23c(ws) + (size_t)br * REP2 * 3072 + off;
                const unsigned long long* he = h23e(ws) + (size_t)br * REP2 * 3072 + off;
                unsigned cR = 0; unsigned long long eR = 0;
                for (int r = 0; r < REP2; r++) { cR += hc[r * 3072 + i]; eR += he[r * 3072 + i]; }
                cv = cR; ev = eR;
            }
            cnt[j] = cv; cev[j] = ev; s += cv;
        }
        __syncthreads();
        pref[t] = s;
        __syncthreads();
        for (int off = 1; off < 256; off <<= 1) {
            unsigned x = (t >= off) ? pref[t - off] : 0u;
            __syncthreads();
            pref[t] += x;
            __syncthreads();
        }
        unsigned tot = pref[255];
        if (target > tot) target = tot;
        unsigned before = pref[t] - s;
        for (int j = 0; j < per; j++) {
            if (before < target && before + cnt[j] >= target) {
                sh_sel = (unsigned)(t * per + j);
                sh_tnext = target - before;
                sh_cb = before;
                sh_ci = before + cnt[j];
            }
            before += cnt[j];
        }
        __syncthreads();
        unsigned sel = sh_sel;
        unsigned long long ceb = 0, cei = 0;
        for (int j = 0; j < per; j++) {
            unsigned bin = (unsigned)(t * per + j);
            if (bin < sel)  ceb += cev[j];
            if (bin <= sel) cei += cev[j];
        }
        ceb = block_reduce(ceb, qscr);
        cei = block_reduce(cei, qscr);
        if (t == 0) {
            if (level == 1) {
                if (haspos && sel == 0 && sh_hA0 == 0) {
                    // bin 0 is pure zeros: threshold = 0.0, selected = all non-neg
                    double ce1 = (double)sumB / (double)CE_SCALE;
                    double cntd = (double)P + (double)((unsigned)N - negn);
                    if (cntd < 1.0) cntd = 1.0;
                    c->loss_score = (CE0 + ce1) / cntd;
                    c->done = 1;
                } else {
                    c->sel1 = sel; c->target = sh_tnext;
                    c->cnt_below = sh_cb; c->ce_below_fx = ceb;
                }
            } else if (level == 2) {
                c->sel2 = sel; c->target = sh_tnext;
                c->cnt_below += sh_cb; c->ce_below_fx += ceb;
            } else {
                double ce1  = (double)(c->ce_below_fx + cei) / (double)CE_SCALE;
                double cntd = (double)c->pos_num + (double)(c->cnt_below + sh_ci);
                if (cntd < 1.0) cntd = 1.0;
                c->loss_score = (c->ce0 + ce1) / cntd;
            }
        }
        __syncthreads();
    }
    if (level == 3 && t == 0) {
        BranchCtrl* c0 = ctrl_of(ws, 0);
        BranchCtrl* c1 = ctrl_of(ws, 1);
        out[0] = (float)(c0->loss_score + c0->loss_bbox + c1->loss_score + c1->loss_bbox);
        out[1] = (float)c0->loss_score;
        out[2] = (float)c0->loss_bbox;
        out[3] = (float)c1->loss_score;
        out[4] = (float)c1->loss_bbox;
    }
}

// ---------------- host ----------------
template <bool S>
static void run_pipeline(const float4* sc0, const float4* bb0, const float4* mk0, const float4* lb0,
                         const float4* sc1, const float4* bb1, const float4* mk1, const float4* lb1,
                         void* ws, float* out, hipStream_t stream)
{
    pass1<S><<<PASS1_GRID, BLK, 0, stream>>>(sc0, bb0, mk0, lb0, sc1, bb1, mk1, lb1, ws);
    scan_pass<<<1, BLK, 0, stream>>>(ws, 1, out);
    refine_pass<S><<<GRID_R, BLK, 0, stream>>>(sc0, lb0, sc1, lb1, ws, 2);
    scan_pass<<<1, BLK, 0, stream>>>(ws, 2, out);
    refine_pass<S><<<GRID_R, BLK, 0, stream>>>(sc0, lb0, sc1, lb1, ws, 3);
    scan_pass<<<1, BLK, 0, stream>>>(ws, 3, out);
}

extern "C" void kernel_launch(void* const* d_in, const int* in_sizes, int n_in,
                              void* d_out, int out_size, void* d_ws, size_t ws_size,
                              hipStream_t stream)
{
    (void)in_sizes; (void)n_in; (void)out_size;
    const float4* sc0 = (const float4*)d_in[0];
    const float4* bb0 = (const float4*)d_in[1];
    const float4* mk0 = (const float4*)d_in[2];
    const float4* lb0 = (const float4*)d_in[3];
    const float4* sc1 = (const float4*)d_in[4];
    const float4* bb1 = (const float4*)d_in[5];
    const float4* mk1 = (const float4*)d_in[6];
    const float4* lb1 = (const float4*)d_in[7];
    float* out = (float*)d_out;

    zero_ws_k<<<(ZERO_WORDS + BLK - 1) / BLK, BLK, 0, stream>>>((unsigned*)d_ws, ZERO_WORDS);

    if (ws_size >= WS_NEED)
        run_pipeline<true>(sc0, bb0, mk0, lb0, sc1, bb1, mk1, lb1, d_ws, out, stream);
    else
        run_pipeline<false>(sc0, bb0, mk0, lb0, sc1, bb1, mk1, lb1, d_ws, out, stream);
}

// Round 4
// 325.716 us; speedup vs baseline: 1.0523x; 1.0523x over previous
//
#include <hip/hip_runtime.h>

using ull = unsigned long long;

// ---------------- problem constants ----------------
constexpr int NB  = 32;
constexpr int HW0 = 320 * 320;
constexpr int HW1 = 160 * 160;
constexpr int N0  = NB * HW0;            // 3,276,800
constexpr int N1  = NB * HW1;            // 819,200
constexpr int HW0_4 = HW0 / 4;
constexpr int HW1_4 = HW1 / 4;
constexpr int BLK = 256;

// score blocks: 2 uint4-packs (8 px) per thread -> 512 packs per block
constexpr int SB0 = N0 / 4 / 512;        // 1600
constexpr int SB1 = N1 / 4 / 512;        // 400
constexpr int SBT = SB0 + SB1;           // 2000
// bbox blocks: 5 float4 per stream per thread, fully unrolled
constexpr int BBLK0 = 2560, BBLK1 = 640; // 3,276,800/(2560*256)=5 ; 819,200/(640*256)=5
constexpr int P1_GRID = SBT + BBLK0 + BBLK1;   // 5200
// refine: 4 uint4-packs (16 px) per thread
constexpr int RB0 = 800, RB1 = 200, GRID_R = RB0 + RB1;
constexpr int RT0 = RB0 * BLK;           // 204,800 (uint4 stride)
constexpr int RT1 = RB1 * BLK;           // 51,200

constexpr float CE_SCALE = 16384.0f;
constexpr ull MASK40 = (1ull << 40) - 1;
constexpr int REP1 = 32, REP2 = 8;

// ---------------- workspace layout (bytes) ----------------
constexpr size_t CTRL_OFF = 0;                                   // BranchCtrl[2]
constexpr size_t H1_OFF  = 4096;                                 // u32 [2][1024][REP1] (bin-major)
constexpr size_t H2_OFF  = H1_OFF + (size_t)2 * 1024 * REP1 * 4; // u32 [2][2048][REP2]
constexpr size_t H3_OFF  = H2_OFF + (size_t)2 * 2048 * REP2 * 4; // u64 [2][1024][REP2]
constexpr size_t FIN_OFF = H3_OFF + (size_t)2 * 1024 * REP2 * 8; // [2][REP2][2] u64 cnt, double ce
constexpr size_t ZERO_END = FIN_OFF + 2 * REP2 * 16;             // 528,640
constexpr int    ZERO_V4  = (int)(ZERO_END / 16);                // 33,040 uint4s
constexpr size_t PN_OFF  = ZERO_END;                             // u32[SBT]
constexpr size_t CEP_OFF = PN_OFF + SBT * 4;                     // double2[SBT] (ce0, ce1nn)
constexpr size_t DM_OFF  = CEP_OFF + (size_t)SBT * 16;           // double2[3200] (d2, ms)
constexpr size_t PB_OFF  = ((DM_OFF + 3200 * 16 + 255) / 256) * 256;
constexpr size_t WS_NEED = PB_OFF + (size_t)(N0 + N1) * 4;       // ~17.04 MB

struct BranchCtrl {
    unsigned pos_num, neg_num, sel1, sel2, target, done, pad0, pad1;
    double ce0, ce1nn, loss_score, loss_bbox;
};

__device__ inline BranchCtrl* ctrl_of(void* ws, int br) { return (BranchCtrl*)((char*)ws + CTRL_OFF) + br; }
__device__ inline unsigned* h1_of(void* ws, int br) { return (unsigned*)((char*)ws + H1_OFF) + (size_t)br * 1024 * REP1; }
__device__ inline unsigned* h2_of(void* ws, int br) { return (unsigned*)((char*)ws + H2_OFF) + (size_t)br * 2048 * REP2; }
__device__ inline ull*      h3_of(void* ws, int br) { return (ull*)((char*)ws + H3_OFF) + (size_t)br * 1024 * REP2; }
__device__ inline ull*      fin_of(void* ws, int br) { return (ull*)((char*)ws + FIN_OFF) + (size_t)br * REP2 * 2; }
__device__ inline unsigned* pn_part(void* ws)  { return (unsigned*)((char*)ws + PN_OFF); }
__device__ inline double2*  cep_part(void* ws) { return (double2*)((char*)ws + CEP_OFF); }
__device__ inline double2*  dm_part(void* ws)  { return (double2*)((char*)ws + DM_OFF); }
__device__ inline unsigned* pb_of(void* ws, int br) { return (unsigned*)((char*)ws + PB_OFF) + (br ? (size_t)N0 : 0); }

// ---------------- reduce helpers ----------------
__device__ __forceinline__ unsigned wred_u(unsigned v) {
#pragma unroll
    for (int o = 32; o > 0; o >>= 1) v += __shfl_down(v, o, 64);
    return v;
}
__device__ __forceinline__ ull wred_q(ull v) {
#pragma unroll
    for (int o = 32; o > 0; o >>= 1) v += __shfl_down(v, o, 64);
    return v;
}
__device__ __forceinline__ double wred_d(double v) {
#pragma unroll
    for (int o = 32; o > 0; o >>= 1) v += __shfl_down(v, o, 64);
    return v;
}

// ---------------- kernels ----------------
__global__ __launch_bounds__(256) void zero_ws_k(uint4* p, int n) {
    int i = blockIdx.x * BLK + threadIdx.x;
    if (i < n) p[i] = make_uint4(0, 0, 0, 0);
}

// ---- pass1 ----
template <int BR, bool STORED>
__device__ void score_body(const float4* __restrict__ score, const float4* __restrict__ glabel,
                           void* ws, int blk, int gblk, unsigned* h)
{
    constexpr int HW4 = BR ? HW1_4 : HW0_4;
    const int t = threadIdx.x;
    const int base = blk * 512 + t;

    float4 s0[2], s1[2], g0[2], g1[2];
    int idx[2] = { base, base + 256 };
#pragma unroll
    for (int u = 0; u < 2; u++) {
        int b = idx[u] / HW4, r = idx[u] - b * HW4;
        const float4* sp = score  + (size_t)(b * 2) * HW4 + r;
        const float4* gp = glabel + (size_t)(b * 6) * HW4 + r;
        s0[u] = sp[0]; s1[u] = sp[HW4];
        g0[u] = gp[0]; g1[u] = gp[HW4];
    }

    unsigned posc = 0, negc = 0;
    float ce0 = 0.0f, ce1 = 0.0f;
#pragma unroll
    for (int u = 0; u < 2; u++) {
        uint4 pk;
        unsigned bins[4];
#pragma unroll
        for (int j = 0; j < 4; j++) {
            float a = (&s0[u].x)[j], cc = (&s1[u].x)[j];
            float m = fmaxf(a, cc);
            float e0 = __expf(a - m), e1 = __expf(cc - m);
            float inv = 1.0f / (e0 + e1);
            float p0 = e0 * inv, p1 = e1 * inv;
            float l0 = (&g0[u].x)[j], l1 = (&g1[u].x)[j];
            bool pos = l0 > 0.5f, neg = l1 > 0.5f;
            posc += pos ? 1u : 0u;
            negc += neg ? 1u : 0u;
            if (pos)  ce0 += -l0 * __logf(p0);
            if (!neg) ce1 += -l1 * __logf(p1);
            unsigned pb = __float_as_uint(p1);
            (&pk.x)[j] = pb | (neg ? 0x80000000u : 0u);
            bins[j] = (neg ? 0u : 512u) + (pb >> 21);
        }
        if (STORED) ((uint4*)pb_of(ws, BR))[idx[u]] = pk;
#pragma unroll
        for (int j = 0; j < 4; j++) {
            unsigned bj = bins[j];
            if (bj != 0xFFFFFFFFu) {
                unsigned cnt = 1;
#pragma unroll
                for (int k = j + 1; k < 4; k++)
                    if (bins[k] == bj) { cnt++; bins[k] = 0xFFFFFFFFu; }
                atomicAdd(&h[bj], cnt);
            }
        }
    }

    unsigned pn = posc | (negc << 16);
    pn = wred_u(pn);
    double C0 = wred_d((double)ce0);
    double C1 = wred_d((double)ce1);
    __shared__ unsigned spn[4];
    __shared__ double sc0[4], sc1[4];
    int w = t >> 6, lane = t & 63;
    if (lane == 0) { spn[w] = pn; sc0[w] = C0; sc1[w] = C1; }
    __syncthreads();   // also orders LDS hist atomics before flush
    if (t == 0) {
        pn_part(ws)[gblk] = spn[0] + spn[1] + spn[2] + spn[3];
        cep_part(ws)[gblk] = make_double2(sc0[0] + sc0[1] + sc0[2] + sc0[3],
                                          sc1[0] + sc1[1] + sc1[2] + sc1[3]);
    }
    const int rep = gblk & (REP1 - 1);
    unsigned* H = h1_of(ws, BR);
    for (int i = t; i < 1024; i += BLK) {
        unsigned v = h[i];
        if (v) atomicAdd(&H[(size_t)i * REP1 + rep], v);
    }
}

template <int BR>
__device__ void bbox_body(const float4* __restrict__ bbox, const float4* __restrict__ gmask,
                          const float4* __restrict__ glabel, void* ws, int blk, int gblk)
{
    constexpr int HW4 = BR ? HW1_4 : HW0_4;
    constexpr int NT  = (BR ? BBLK1 : BBLK0) * BLK;
    const int t = threadIdx.x;
    const int i0 = blk * BLK + t;
    float d2 = 0.0f, ms = 0.0f;
#pragma unroll
    for (int k = 0; k < 5; k++) {
        int i = i0 + k * NT;
        int b = i / (4 * HW4);
        int off = i + (2 * b + 2) * HW4;
        float4 pb4 = bbox[i];
        float4 gm  = gmask[off];
        float4 gl  = glabel[off];
#pragma unroll
        for (int j = 0; j < 4; j++) {
            float m = (&gm.x)[j];
            float d = ((&pb4.x)[j] - (&gl.x)[j]) * m;
            d2 += d * d;
            ms += m;
        }
    }
    double D = wred_d((double)d2);
    double M = wred_d((double)ms);
    __shared__ double sdd[4], sdm[4];
    int w = t >> 6, lane = t & 63;
    if (lane == 0) { sdd[w] = D; sdm[w] = M; }
    __syncthreads();
    if (t == 0)
        dm_part(ws)[gblk] = make_double2(sdd[0] + sdd[1] + sdd[2] + sdd[3],
                                         sdm[0] + sdm[1] + sdm[2] + sdm[3]);
}

template <bool STORED>
__global__ __launch_bounds__(256, 4) void pass1(
    const float4* __restrict__ sc0, const float4* __restrict__ bb0,
    const float4* __restrict__ mk0, const float4* __restrict__ lb0,
    const float4* __restrict__ sc1, const float4* __restrict__ bb1,
    const float4* __restrict__ mk1, const float4* __restrict__ lb1,
    void* ws)
{
    __shared__ unsigned h[1024];
    const int bid = blockIdx.x;
    if (bid < SBT) {
        for (int i = threadIdx.x; i < 1024; i += BLK) h[i] = 0;
        __syncthreads();
        if (bid < SB0) score_body<0, STORED>(sc0, lb0, ws, bid, bid, h);
        else           score_body<1, STORED>(sc1, lb1, ws, bid - SB0, bid, h);
    } else if (bid < SBT + BBLK0) {
        bbox_body<0>(bb0, mk0, lb0, ws, bid - SBT, bid - SBT);
    } else {
        bbox_body<1>(bb1, mk1, lb1, ws, bid - SBT - BBLK0, bid - SBT);
    }
}

// ---- refine2: count hist of mid-bits within sel1 bin ----
template <int BR, bool STORED>
__device__ void refine2_body(const float4* __restrict__ score, const float4* __restrict__ glabel,
                             void* ws, int blk, unsigned* h)
{
    BranchCtrl* c = ctrl_of(ws, BR);
    const unsigned haspos = (c->pos_num > 0) ? 1u : 0u;
    const unsigned sel1 = c->sel1;
    constexpr int T = BR ? RT1 : RT0;
    constexpr int HW4 = BR ? HW1_4 : HW0_4;
    const int base = blk * BLK + (int)threadIdx.x;

    unsigned pk[16];
    if (STORED) {
        const uint4* pb4 = (const uint4*)pb_of(ws, BR);
#pragma unroll
        for (int i = 0; i < 4; i++) {
            uint4 q = pb4[base + i * T];
            pk[i*4+0]=q.x; pk[i*4+1]=q.y; pk[i*4+2]=q.z; pk[i*4+3]=q.w;
        }
    } else {
#pragma unroll
        for (int i = 0; i < 4; i++) {
            int id = base + i * T;
            int b = id / HW4, r = id - b * HW4;
            float4 s0 = score[(size_t)(b*2)*HW4 + r];
            float4 s1 = score[(size_t)(b*2+1)*HW4 + r];
            float4 g1 = glabel[(size_t)(b*6+1)*HW4 + r];
#pragma unroll
            for (int j = 0; j < 4; j++) {
                float a=(&s0.x)[j], cc=(&s1.x)[j];
                float m=fmaxf(a,cc);
                float e0=__expf(a-m), e1=__expf(cc-m);
                float p1=e1/(e0+e1);
                pk[i*4+j] = __float_as_uint(p1) | (((&g1.x)[j] > 0.5f) ? 0x80000000u : 0u);
            }
        }
    }
    unsigned z = 0;
#pragma unroll
    for (int i = 0; i < 4; i++) {
        unsigned bins[4];
#pragma unroll
        for (int j = 0; j < 4; j++) {
            unsigned raw = pk[i*4+j], pbv = raw & 0x7FFFFFFFu;
            unsigned npb = haspos ? ((raw >> 31) ? pbv : 0u) : pbv;
            bool m = (npb >> 21) == sel1;
            if (m && npb == 0) { z++; bins[j] = 0xFFFFFFFFu; }
            else bins[j] = m ? ((npb >> 10) & 0x7FFu) : 0xFFFFFFFFu;
        }
#pragma unroll
        for (int j = 0; j < 4; j++) {
            unsigned bj = bins[j];
            if (bj != 0xFFFFFFFFu) {
                unsigned cnt = 1;
#pragma unroll
                for (int k = j + 1; k < 4; k++)
                    if (bins[k] == bj) { cnt++; bins[k] = 0xFFFFFFFFu; }
                atomicAdd(&h[bj], cnt);
            }
        }
    }
    if (z) atomicAdd(&h[0], z);
}

template <bool STORED>
__global__ __launch_bounds__(256) void refine2(
    const float4* __restrict__ sc0, const float4* __restrict__ lb0,
    const float4* __restrict__ sc1, const float4* __restrict__ lb1, void* ws)
{
    int br, blk;
    if (blockIdx.x < RB0) { br = 0; blk = blockIdx.x; }
    else                  { br = 1; blk = blockIdx.x - RB0; }
    if (ctrl_of(ws, br)->done) return;

    __shared__ unsigned h[2048];
    for (int i = threadIdx.x; i < 2048; i += BLK) h[i] = 0;
    __syncthreads();
    if (br == 0) refine2_body<0, STORED>(sc0, lb0, ws, blk, h);
    else         refine2_body<1, STORED>(sc1, lb1, ws, blk, h);
    __syncthreads();
    const int rep = blockIdx.x & (REP2 - 1);
    unsigned* H = h2_of(ws, br);
    for (int i = threadIdx.x; i < 2048; i += BLK) {
        unsigned v = h[i];
        if (v) atomicAdd(&H[(size_t)i * REP2 + rep], v);
    }
}

// ---- refine3: low-bits hist (cnt+cefx) within sel1:sel2, plus strictly-below gather ----
template <int BR, bool STORED>
__device__ void refine3_body(const float4* __restrict__ score, const float4* __restrict__ glabel,
                             void* ws, int blk, int gblk, ull* h)
{
    BranchCtrl* c = ctrl_of(ws, BR);
    const unsigned haspos = (c->pos_num > 0) ? 1u : 0u;
    const unsigned sel1 = c->sel1, sel2 = c->sel2;
    const unsigned sel12 = (sel1 << 11) | sel2;
    constexpr int T = BR ? RT1 : RT0;
    constexpr int HW4 = BR ? HW1_4 : HW0_4;
    constexpr int HW  = BR ? HW1 : HW0;
    const int base = blk * BLK + (int)threadIdx.x;
    const float* glab_s = (const float*)glabel;

    unsigned pk[16];
    float g1v[16];
    if (STORED) {
        const uint4* pb4 = (const uint4*)pb_of(ws, BR);
#pragma unroll
        for (int i = 0; i < 4; i++) {
            uint4 q = pb4[base + i * T];
            pk[i*4+0]=q.x; pk[i*4+1]=q.y; pk[i*4+2]=q.z; pk[i*4+3]=q.w;
        }
    } else {
#pragma unroll
        for (int i = 0; i < 4; i++) {
            int id = base + i * T;
            int b = id / HW4, r = id - b * HW4;
            float4 s0 = score[(size_t)(b*2)*HW4 + r];
            float4 s1 = score[(size_t)(b*2+1)*HW4 + r];
            float4 g1 = glabel[(size_t)(b*6+1)*HW4 + r];
#pragma unroll
            for (int j = 0; j < 4; j++) {
                float a=(&s0.x)[j], cc=(&s1.x)[j];
                float m=fmaxf(a,cc);
                float e0=__expf(a-m), e1=__expf(cc-m);
                float p1=e1/(e0+e1);
                pk[i*4+j] = __float_as_uint(p1) | (((&g1.x)[j] > 0.5f) ? 0x80000000u : 0u);
                g1v[i*4+j] = (&g1.x)[j];
            }
        }
    }

    ull cnt_lt = 0;
    double ce_lt = 0.0;
    ull zpack = 0;
#pragma unroll
    for (int i = 0; i < 4; i++) {
#pragma unroll
        for (int j = 0; j < 4; j++) {
            unsigned raw = pk[i*4+j], pbv = raw & 0x7FFFFFFFu;
            unsigned npb = haspos ? ((raw >> 31) ? pbv : 0u) : pbv;
            bool iszero = (npb == 0);
            if (iszero && sel12 != 0) continue;  // accounted via base in scan3
            unsigned b1 = npb >> 21, b2 = (npb >> 10) & 0x7FFu;
            bool lt = (b1 < sel1) || (b1 == sel1 && b2 < sel2);
            bool eq = ((npb >> 10) == sel12);
            if (lt || eq) {
                float g1s;
                if (STORED) {
                    int px = (base + i * T) * 4 + j;
                    int bb = px / HW, rr = px - bb * HW;
                    g1s = glab_s[(size_t)(bb * 6 + 1) * HW + rr];
                } else {
                    g1s = g1v[i*4+j];
                }
                float ce = -g1s * __logf(__uint_as_float(pbv));
                if (lt) { cnt_lt++; ce_lt += (double)ce; }
                else {
                    ull v = (1ull << 40) | (ull)__float2uint_rn(ce * CE_SCALE);
                    if (iszero) zpack += v;
                    else atomicAdd(&h[npb & 0x3FFu], v);
                }
            }
        }
    }
    if (zpack) atomicAdd(&h[0], zpack);

    ull CL = wred_q(cnt_lt);
    double CE = wred_d(ce_lt);
    __shared__ ull sq[4];
    __shared__ double sd[4];
    int t = threadIdx.x, w = t >> 6, lane = t & 63;
    if (lane == 0) { sq[w] = CL; sd[w] = CE; }
    __syncthreads();   // also orders LDS hist atomics before flush
    if (t == 0) {
        ull totc = sq[0] + sq[1] + sq[2] + sq[3];
        double totd = sd[0] + sd[1] + sd[2] + sd[3];
        ull* F = fin_of(ws, BR) + (size_t)(gblk & (REP2 - 1)) * 2;
        if (totc) atomicAdd(&F[0], totc);
        if (totd != 0.0) atomicAdd((double*)&F[1], totd);
    }
    const int rep = gblk & (REP2 - 1);
    ull* H = h3_of(ws, BR);
    for (int i = t; i < 1024; i += BLK) {
        ull v = h[i];
        if (v) atomicAdd(&H[(size_t)i * REP2 + rep], v);
    }
}

template <bool STORED>
__global__ __launch_bounds__(256) void refine3(
    const float4* __restrict__ sc0, const float4* __restrict__ lb0,
    const float4* __restrict__ sc1, const float4* __restrict__ lb1, void* ws)
{
    int br, blk;
    if (blockIdx.x < RB0) { br = 0; blk = blockIdx.x; }
    else                  { br = 1; blk = blockIdx.x - RB0; }
    if (ctrl_of(ws, br)->done) return;

    __shared__ ull h[1024];
    for (int i = threadIdx.x; i < 1024; i += BLK) h[i] = 0;
    __syncthreads();
    if (br == 0) refine3_body<0, STORED>(sc0, lb0, ws, blk, blockIdx.x, h);
    else         refine3_body<1, STORED>(sc1, lb1, ws, blk, blockIdx.x, h);
}

// ---- scan/select (single block), level in {1,2,3}; level 3 finalizes output ----
__global__ __launch_bounds__(256) void scan_pass(void* ws, int level, float* out)
{
    const int t = threadIdx.x;
    __shared__ unsigned pref[256];
    __shared__ unsigned sh_sel, sh_tnext, sh_hA0;
    __shared__ unsigned shP[2], shN[2];
    __shared__ double shCE0[2], shCE1[2];
    __shared__ ull qscr[4];

    if (level == 1) {
        ull pn0 = 0, pn1 = 0;
        double a0=0, b0=0, a1=0, b1=0, d20=0, ms0=0, d21=0, ms1=0;
        const unsigned* PN = pn_part(ws);
        const double2* CP = cep_part(ws);
        for (int i = t; i < SBT; i += BLK) {
            unsigned v = PN[i];
            double2 ce = CP[i];
            ull pv = (ull)(v & 0xFFFFu) | ((ull)(v >> 16) << 32);
            if (i < SB0) { pn0 += pv; a0 += ce.x; b0 += ce.y; }
            else         { pn1 += pv; a1 += ce.x; b1 += ce.y; }
        }
        const double2* DM = dm_part(ws);
        for (int i = t; i < BBLK0 + BBLK1; i += BLK) {
            double2 d = DM[i];
            if (i < BBLK0) { d20 += d.x; ms0 += d.y; }
            else           { d21 += d.x; ms1 += d.y; }
        }
        pn0 = wred_q(pn0); pn1 = wred_q(pn1);
        a0 = wred_d(a0); b0 = wred_d(b0); a1 = wred_d(a1); b1 = wred_d(b1);
        d20 = wred_d(d20); ms0 = wred_d(ms0); d21 = wred_d(d21); ms1 = wred_d(ms1);
        __shared__ ull qs[2][4];
        __shared__ double ds[8][4];
        int w = t >> 6;
        if ((t & 63) == 0) {
            qs[0][w]=pn0; qs[1][w]=pn1;
            ds[0][w]=a0; ds[1][w]=b0; ds[2][w]=a1; ds[3][w]=b1;
            ds[4][w]=d20; ds[5][w]=ms0; ds[6][w]=d21; ds[7][w]=ms1;
        }
        __syncthreads();
        if (t == 0) {
            ull P0=qs[0][0]+qs[0][1]+qs[0][2]+qs[0][3];
            ull P1=qs[1][0]+qs[1][1]+qs[1][2]+qs[1][3];
            double A0=ds[0][0]+ds[0][1]+ds[0][2]+ds[0][3];
            double B0=ds[1][0]+ds[1][1]+ds[1][2]+ds[1][3];
            double A1=ds[2][0]+ds[2][1]+ds[2][2]+ds[2][3];
            double B1=ds[3][0]+ds[3][1]+ds[3][2]+ds[3][3];
            double D0=ds[4][0]+ds[4][1]+ds[4][2]+ds[4][3];
            double M0=ds[5][0]+ds[5][1]+ds[5][2]+ds[5][3];
            double D1=ds[6][0]+ds[6][1]+ds[6][2]+ds[6][3];
            double M1=ds[7][0]+ds[7][1]+ds[7][2]+ds[7][3];
            shP[0]=(unsigned)(P0 & 0xFFFFFFFFu); shN[0]=(unsigned)(P0 >> 32);
            shP[1]=(unsigned)(P1 & 0xFFFFFFFFu); shN[1]=(unsigned)(P1 >> 32);
            shCE0[0]=A0; shCE1[0]=B0; shCE0[1]=A1; shCE1[1]=B1;
            BranchCtrl* c0 = ctrl_of(ws, 0);
            BranchCtrl* c1 = ctrl_of(ws, 1);
            c0->pos_num=shP[0]; c0->neg_num=shN[0]; c0->ce0=A0; c0->ce1nn=B0;
            c1->pos_num=shP[1]; c1->neg_num=shN[1]; c1->ce0=A1; c1->ce1nn=B1;
            c0->loss_bbox = (M0 > 0.0) ? D0 / fmax(M0, 1e-8) : 0.0;
            c1->loss_bbox = (M1 > 0.0) ? D1 / fmax(M1, 1e-8) : 0.0;
        }
        __syncthreads();
    }

    for (int br = 0; br < 2; br++) {
        BranchCtrl* c = ctrl_of(ws, br);
        const unsigned N = br ? N1 : N0;
        unsigned target, haspos, negn, P;
        double CE0, CE1NN;
        if (level == 1) {
            P = shP[br]; negn = shN[br]; CE0 = shCE0[br]; CE1NN = shCE1[br];
            haspos = (P > 0) ? 1u : 0u;
            unsigned k = haspos ? ((5u * P < negn) ? 5u * P : negn) : (N / 10u);
            target = (k < 1u) ? 1u : k;
            if (target > N) target = N;
        } else {
            if (c->done) continue;
            P = c->pos_num; negn = c->neg_num; haspos = (P > 0) ? 1u : 0u;
            target = c->target; CE0 = c->ce0; CE1NN = c->ce1nn;
        }

        const int per = (level == 1) ? 2 : (level == 2) ? 8 : 4;
        unsigned cnt[8];
        ull cev[4];
        unsigned ssum = 0;
        if (level == 1) {
            const unsigned* H = h1_of(ws, br);
            for (int j = 0; j < 2; j++) {
                int i = t * 2 + j;
                const uint4* p = (const uint4*)(H + (size_t)i * REP1);
                unsigned s = 0;
#pragma unroll
                for (int r = 0; r < REP1 / 4; r++) { uint4 q = p[r]; s += q.x + q.y + q.z + q.w; }
                if (i == 0) sh_hA0 = s;
                if (!haspos) {
                    const uint4* p2 = (const uint4*)(H + (size_t)(512 + i) * REP1);
#pragma unroll
                    for (int r = 0; r < REP1 / 4; r++) { uint4 q = p2[r]; s += q.x + q.y + q.z + q.w; }
                }
                unsigned cv = s + ((haspos && i == 0) ? (N - negn) : 0u);
                cnt[j] = cv; ssum += cv;
            }
        } else if (level == 2) {
            const unsigned* H = h2_of(ws, br);
            for (int j = 0; j < 8; j++) {
                int i = t * 8 + j;
                const uint4* p = (const uint4*)(H + (size_t)i * REP2);
                uint4 q0 = p[0], q1 = p[1];
                cnt[j] = q0.x + q0.y + q0.z + q0.w + q1.x + q1.y + q1.z + q1.w;
                ssum += cnt[j];
            }
        } else {
            const ull* H = h3_of(ws, br);
            for (int j = 0; j < 4; j++) {
                int i = t * 4 + j;
                ull e = 0;
#pragma unroll
                for (int r = 0; r < REP2; r++) e += H[(size_t)i * REP2 + r];
                cev[j] = e;
                cnt[j] = (unsigned)(e >> 40);
                ssum += cnt[j];
            }
        }
        if (t == 0) { sh_sel = 0; sh_tnext = 1; }
        __syncthreads();
        pref[t] = ssum;
        __syncthreads();
        for (int off = 1; off < 256; off <<= 1) {
            unsigned x = (t >= off) ? pref[t - off] : 0u;
            __syncthreads();
            pref[t] += x;
            __syncthreads();
        }
        unsigned tot = pref[255];
        if (target > tot) target = tot;
        unsigned before = pref[t] - ssum;
        for (int j = 0; j < per; j++) {
            if (tot && before < target && before + cnt[j] >= target) {
                sh_sel = (unsigned)(t * per + j);
                sh_tnext = target - before;
            }
            before += cnt[j];
        }
        __syncthreads();
        unsigned sel = sh_sel;

        if (level == 3) {
            ull cei = 0;
            for (int j = 0; j < per; j++) {
                unsigned bin = (unsigned)(t * per + j);
                if (bin <= sel) cei += cev[j];
            }
            cei = wred_q(cei);
            int w = t >> 6;
            if ((t & 63) == 0) qscr[w] = cei;
            __syncthreads();
            if (t == 0) {
                ull CEI = qscr[0] + qscr[1] + qscr[2] + qscr[3];
                const ull* F = fin_of(ws, br);
                ull cl = 0; double cel = 0.0;
                for (int r = 0; r < REP2; r++) {
                    cl += F[r * 2];
                    cel += ((const double*)F)[r * 2 + 1];
                }
                unsigned sel12 = (c->sel1 << 11) | c->sel2;
                double basec = (haspos && sel12 != 0) ? (double)(N - negn) : 0.0;
                double basee = (haspos && sel12 != 0) ? CE1NN : 0.0;
                double cntd = (double)P + basec + (double)cl + (double)(CEI >> 40);
                if (cntd < 1.0) cntd = 1.0;
                double ce = CE0 + basee + cel + (double)(CEI & MASK40) / (double)CE_SCALE;
                c->loss_score = ce / cntd;
            }
            __syncthreads();
        } else if (t == 0) {
            if (level == 1) {
                if (haspos && sel == 0 && sh_hA0 == 0) {
                    double cntd = (double)P + (double)(N - negn);
                    if (cntd < 1.0) cntd = 1.0;
                    c->loss_score = (CE0 + CE1NN) / cntd;
                    c->done = 1;
                } else {
                    c->sel1 = sel; c->target = sh_tnext;
                }
            } else {
                c->sel2 = sel; c->target = sh_tnext;
            }
        }
        __syncthreads();
    }

    if (level == 3 && t == 0) {
        BranchCtrl* c0 = ctrl_of(ws, 0);
        BranchCtrl* c1 = ctrl_of(ws, 1);
        out[0] = (float)(c0->loss_score + c0->loss_bbox + c1->loss_score + c1->loss_bbox);
        out[1] = (float)c0->loss_score;
        out[2] = (float)c0->loss_bbox;
        out[3] = (float)c1->loss_score;
        out[4] = (float)c1->loss_bbox;
    }
}

// ---------------- host ----------------
template <bool S>
static void run_pipeline(const float4* sc0, const float4* bb0, const float4* mk0, const float4* lb0,
                         const float4* sc1, const float4* bb1, const float4* mk1, const float4* lb1,
                         void* ws, float* out, hipStream_t stream)
{
    pass1<S><<<P1_GRID, BLK, 0, stream>>>(sc0, bb0, mk0, lb0, sc1, bb1, mk1, lb1, ws);
    scan_pass<<<1, BLK, 0, stream>>>(ws, 1, out);
    refine2<S><<<GRID_R, BLK, 0, stream>>>(sc0, lb0, sc1, lb1, ws);
    scan_pass<<<1, BLK, 0, stream>>>(ws, 2, out);
    refine3<S><<<GRID_R, BLK, 0, stream>>>(sc0, lb0, sc1, lb1, ws);
    scan_pass<<<1, BLK, 0, stream>>>(ws, 3, out);
}

extern "C" void kernel_launch(void* const* d_in, const int* in_sizes, int n_in,
                              void* d_out, int out_size, void* d_ws, size_t ws_size,
                              hipStream_t stream)
{
    (void)in_sizes; (void)n_in; (void)out_size;
    const float4* sc0 = (const float4*)d_in[0];
    const float4* bb0 = (const float4*)d_in[1];
    const float4* mk0 = (const float4*)d_in[2];
    const float4* lb0 = (const float4*)d_in[3];
    const float4* sc1 = (const float4*)d_in[4];
    const float4* bb1 = (const float4*)d_in[5];
    const float4* mk1 = (const float4*)d_in[6];
    const float4* lb1 = (const float4*)d_in[7];
    float* out = (float*)d_out;

    zero_ws_k<<<(ZERO_V4 + BLK - 1) / BLK, BLK, 0, stream>>>((uint4*)d_ws, ZERO_V4);

    if (ws_size >= WS_NEED)
        run_pipeline<true>(sc0, bb0, mk0, lb0, sc1, bb1, mk1, lb1, d_ws, out, stream);
    else
        run_pipeline<false>(sc0, bb0, mk0, lb0, sc1, bb1, mk1, lb1, d_ws, out, stream);
}